// Round 1
// baseline (184.197 us; speedup 1.0000x reference)
//
#include <hip/hip_runtime.h>
#include <cstdint>
#include <cstddef>

typedef __bf16 bf16x8 __attribute__((ext_vector_type(8)));
typedef float f32x4 __attribute__((ext_vector_type(4)));
typedef short s16x8 __attribute__((ext_vector_type(8)));
typedef unsigned short u16x4 __attribute__((ext_vector_type(4)));

#define S_LEN 2048
#define DH    64
#define BM    64
#define BK    64
#define NTILE (S_LEN / BK)   // 32 K/V tiles

static __device__ __forceinline__ unsigned short f2bf(float x) {
    unsigned int u = __builtin_bit_cast(unsigned int, x);
    u += 0x7FFFu + ((u >> 16) & 1u);   // RNE
    return (unsigned short)(u >> 16);
}
static __device__ __forceinline__ float bf2f(unsigned short h) {
    unsigned int u = ((unsigned int)h) << 16;
    return __builtin_bit_cast(float, u);
}

// swizzled ushort index inside a [rows][64] bf16 LDS tile:
// phys = row*64 + (col ^ ((row&7)<<3))  -- spreads 16B column-slices across banks
static __device__ __forceinline__ int swz(int row, int col) {
    return row * 64 + (col ^ ((row & 7) << 3));
}

__global__ __launch_bounds__(256) void sdpa_fwd(
        const float* __restrict__ Q, const float* __restrict__ K,
        const float* __restrict__ V, float* __restrict__ O)
{
    __shared__ __attribute__((aligned(16))) unsigned short Kl[BK * DH];     // [key][d]
    __shared__ __attribute__((aligned(16))) unsigned short Vt[DH * BK];     // [d][key]
    __shared__ __attribute__((aligned(16))) unsigned short Pl[4][16 * BK];  // per-wave [q][key]

    const int tid = threadIdx.x;
    const int w   = tid >> 6;    // wave 0..3
    const int ln  = tid & 63;
    const int lg  = ln >> 4;     // lane group 0..3
    const int lr  = ln & 15;

    const int n  = blockIdx.x >> 5;    // head (2048/64 = 32 q-tiles per head)
    const int qt = blockIdx.x & 31;
    const int q0 = qt * BM + w * 16;   // this wave's 16 q-rows

    const size_t hoff = (size_t)n * S_LEN * DH;
    const float* __restrict__ Qh = Q + hoff;
    const float* __restrict__ Kh = K + hoff;
    const float* __restrict__ Vh = V + hoff;
    float* __restrict__ Oh = O + hoff;

    // ---- Q fragments in registers, pre-scaled by 1/sqrt(64) = 0.125 (exact in bf16)
    // A-frag for 16x16x32: lane holds Q[q0+lr][t*32 + lg*8 + i], i=0..7
    s16x8 qf[2];
    #pragma unroll
    for (int t = 0; t < 2; ++t) {
        const float* src = Qh + (size_t)(q0 + lr) * DH + t * 32 + lg * 8;
        float4 a = *(const float4*)(src);
        float4 b = *(const float4*)(src + 4);
        s16x8 v;
        v[0] = (short)f2bf(a.x * 0.125f); v[1] = (short)f2bf(a.y * 0.125f);
        v[2] = (short)f2bf(a.z * 0.125f); v[3] = (short)f2bf(a.w * 0.125f);
        v[4] = (short)f2bf(b.x * 0.125f); v[5] = (short)f2bf(b.y * 0.125f);
        v[6] = (short)f2bf(b.z * 0.125f); v[7] = (short)f2bf(b.w * 0.125f);
        qf[t] = v;
    }

    // ---- online-softmax state (per lane: 4 q-rows, r = lg*4 + j, replicated
    //      across the 16 lanes of the group)
    float mrow[4] = {-INFINITY, -INFINITY, -INFINITY, -INFINITY};
    float lrow[4] = {0.f, 0.f, 0.f, 0.f};
    f32x4 oacc[4];   // O D-frags: oacc[nn][j] = O[lg*4+j][nn*16+lr]
    #pragma unroll
    for (int nn = 0; nn < 4; ++nn) oacc[nn] = (f32x4){0.f, 0.f, 0.f, 0.f};

    for (int it = 0; it < NTILE; ++it) {
        const int k0 = it * BK;
        __syncthreads();   // previous tile's LDS reads complete

        // ---- stage K (row-major bf16) and V (transposed bf16) into LDS
        #pragma unroll
        for (int r4 = 0; r4 < 4; ++r4) {
            const int lin = tid + 256 * r4;   // 0..1023
            const int row = lin >> 4;         // key row 0..63
            const int c4  = lin & 15;         // float4 column
            float4 kv = *(const float4*)(Kh + (size_t)(k0 + row) * DH + c4 * 4);
            u16x4 kb;
            kb[0] = f2bf(kv.x); kb[1] = f2bf(kv.y);
            kb[2] = f2bf(kv.z); kb[3] = f2bf(kv.w);
            *(u16x4*)&Kl[swz(row, c4 * 4)] = kb;

            float4 vv = *(const float4*)(Vh + (size_t)(k0 + row) * DH + c4 * 4);
            const float vals[4] = {vv.x, vv.y, vv.z, vv.w};
            #pragma unroll
            for (int ii = 0; ii < 4; ++ii) {
                const int d = c4 * 4 + ii;
                Vt[swz(d, row)] = f2bf(vals[ii]);   // Vt[d][key]
            }
        }
        __syncthreads();

        // ---- S = Q K^T (scaled): 4 key-subtiles of 16, two k-steps of 32
        f32x4 sacc[4];
        #pragma unroll
        for (int kt = 0; kt < 4; ++kt) {
            f32x4 acc = (f32x4){0.f, 0.f, 0.f, 0.f};
            #pragma unroll
            for (int t = 0; t < 2; ++t) {
                // B-frag: lane holds K[kt*16+lr][t*32 + lg*8 + i]
                s16x8 kf = *(const s16x8*)&Kl[swz(kt * 16 + lr, t * 32 + lg * 8)];
                acc = __builtin_amdgcn_mfma_f32_16x16x32_bf16(
                        __builtin_bit_cast(bf16x8, qf[t]),
                        __builtin_bit_cast(bf16x8, kf), acc, 0, 0, 0);
            }
            sacc[kt] = acc;
        }

        // ---- online softmax (rows r = lg*4+j, cols spread over 16 lanes x 4 kt)
        float alpha[4];
        #pragma unroll
        for (int j = 0; j < 4; ++j) {
            float v = fmaxf(fmaxf(sacc[0][j], sacc[1][j]),
                            fmaxf(sacc[2][j], sacc[3][j]));
            #pragma unroll
            for (int off = 1; off < 16; off <<= 1) v = fmaxf(v, __shfl_xor(v, off));
            const float mn = fmaxf(mrow[j], v);
            alpha[j] = __expf(mrow[j] - mn);   // first tile: exp(-inf)=0
            mrow[j] = mn;
        }
        float psum[4] = {0.f, 0.f, 0.f, 0.f};
        #pragma unroll
        for (int kt = 0; kt < 4; ++kt) {
            #pragma unroll
            for (int j = 0; j < 4; ++j) {
                const float p = __expf(sacc[kt][j] - mrow[j]);
                const unsigned short pb = f2bf(p);
                psum[j] += bf2f(pb);            // denominator matches bf16 numerator
                const int r = lg * 4 + j;
                Pl[w][swz(r, kt * 16 + lr)] = pb;
            }
        }
        #pragma unroll
        for (int j = 0; j < 4; ++j) {
            float s = psum[j];
            #pragma unroll
            for (int off = 1; off < 16; off <<= 1) s += __shfl_xor(s, off);
            lrow[j] = lrow[j] * alpha[j] + s;
        }
        #pragma unroll
        for (int nn = 0; nn < 4; ++nn) {
            #pragma unroll
            for (int j = 0; j < 4; ++j) oacc[nn][j] *= alpha[j];
        }

        // ---- O += P V : A-frag from Pl (wave-private), B-frag from Vt
        #pragma unroll
        for (int t = 0; t < 2; ++t) {
            s16x8 pf = *(const s16x8*)&Pl[w][swz(lr, t * 32 + lg * 8)];
            #pragma unroll
            for (int nn = 0; nn < 4; ++nn) {
                s16x8 vf = *(const s16x8*)&Vt[swz(nn * 16 + lr, t * 32 + lg * 8)];
                oacc[nn] = __builtin_amdgcn_mfma_f32_16x16x32_bf16(
                        __builtin_bit_cast(bf16x8, pf),
                        __builtin_bit_cast(bf16x8, vf), oacc[nn], 0, 0, 0);
            }
        }
    }

    // ---- epilogue: normalize and store fp32
    #pragma unroll
    for (int j = 0; j < 4; ++j) {
        const float inv = 1.0f / lrow[j];
        #pragma unroll
        for (int nn = 0; nn < 4; ++nn) {
            Oh[(size_t)(q0 + lg * 4 + j) * DH + nn * 16 + lr] = oacc[nn][j] * inv;
        }
    }
}

extern "C" void kernel_launch(void* const* d_in, const int* in_sizes, int n_in,
                              void* d_out, int out_size, void* d_ws, size_t ws_size,
                              hipStream_t stream) {
    const float* Q = (const float*)d_in[0];
    const float* K = (const float*)d_in[1];
    const float* V = (const float*)d_in[2];
    float* O = (float*)d_out;
    const int n_heads = in_sizes[0] / (S_LEN * DH);       // 32
    const int grid = n_heads * (S_LEN / BM);              // 32 * 32 = 1024
    sdpa_fwd<<<grid, 256, 0, stream>>>(Q, K, V, O);
}

// Round 2
// 125.506 us; speedup vs baseline: 1.4676x; 1.4676x over previous
//
#include <hip/hip_runtime.h>
#include <cstdint>
#include <cstddef>

typedef __bf16 bf16x8 __attribute__((ext_vector_type(8)));
typedef float f32x4 __attribute__((ext_vector_type(4)));
typedef short s16x8 __attribute__((ext_vector_type(8)));
typedef unsigned short u16x4 __attribute__((ext_vector_type(4)));
typedef unsigned short u16x8 __attribute__((ext_vector_type(8)));

#define S_LEN 2048
#define DH    64
#define BM    64
#define BK    64
#define NTILE (S_LEN / BK)
#define NH    32

typedef const __attribute__((address_space(1))) void* gas_ptr;
typedef __attribute__((address_space(3))) void* las_ptr;

static __device__ __forceinline__ unsigned short f2bf(float x) {
    unsigned int u = __builtin_bit_cast(unsigned int, x);
    u += 0x7FFFu + ((u >> 16) & 1u);   // RNE
    return (unsigned short)(u >> 16);
}
static __device__ __forceinline__ float bf2f(unsigned short h) {
    unsigned int u = ((unsigned int)h) << 16;
    return __builtin_bit_cast(float, u);
}

// swizzled ushort index inside a [rows][64] bf16 LDS tile
static __device__ __forceinline__ int swz(int row, int col) {
    return row * 64 + (col ^ ((row & 7) << 3));
}

// ---------------- pre-pass: fp32 -> bf16 (Q scaled), K ----------------
__global__ __launch_bounds__(256) void conv_qk(
        const float* __restrict__ Q, const float* __restrict__ K,
        unsigned short* __restrict__ Qb, unsigned short* __restrict__ Kb, int n8)
{
    const int i = blockIdx.x * 256 + threadIdx.x;
    if (i >= n8) return;
    {
        float4 a = ((const float4*)Q)[2 * i], b = ((const float4*)Q)[2 * i + 1];
        u16x8 o;
        o[0] = f2bf(a.x * 0.125f); o[1] = f2bf(a.y * 0.125f);
        o[2] = f2bf(a.z * 0.125f); o[3] = f2bf(a.w * 0.125f);
        o[4] = f2bf(b.x * 0.125f); o[5] = f2bf(b.y * 0.125f);
        o[6] = f2bf(b.z * 0.125f); o[7] = f2bf(b.w * 0.125f);
        *(u16x8*)&Qb[(size_t)i * 8] = o;
    }
    {
        float4 a = ((const float4*)K)[2 * i], b = ((const float4*)K)[2 * i + 1];
        u16x8 o;
        o[0] = f2bf(a.x); o[1] = f2bf(a.y); o[2] = f2bf(a.z); o[3] = f2bf(a.w);
        o[4] = f2bf(b.x); o[5] = f2bf(b.y); o[6] = f2bf(b.z); o[7] = f2bf(b.w);
        *(u16x8*)&Kb[(size_t)i * 8] = o;
    }
}

// ---------------- pre-pass: V -> V^T bf16 per head --------------------
__global__ __launch_bounds__(256) void conv_vt(
        const float* __restrict__ V, unsigned short* __restrict__ Vt)
{
    __shared__ unsigned short tile[64][72];   // +8 pad: rotate banks
    const int tid = threadIdx.x;
    const int n  = blockIdx.x >> 5;
    const int s0 = (blockIdx.x & 31) * 64;
    const float* Vh = V + (size_t)n * S_LEN * DH + (size_t)s0 * DH;

    #pragma unroll
    for (int r4 = 0; r4 < 4; ++r4) {
        const int lin = tid + 256 * r4;
        const int row = lin >> 4;     // s within tile
        const int c4  = lin & 15;     // float4 col
        float4 v = *(const float4*)(Vh + (size_t)row * DH + c4 * 4);
        u16x4 b;
        b[0] = f2bf(v.x); b[1] = f2bf(v.y); b[2] = f2bf(v.z); b[3] = f2bf(v.w);
        *(u16x4*)&tile[row][c4 * 4] = b;
    }
    __syncthreads();
    #pragma unroll
    for (int p = 0; p < 2; ++p) {
        const int cid = tid + 256 * p;    // 0..511
        const int d  = cid >> 3;
        const int sc = cid & 7;
        u16x8 o;
        #pragma unroll
        for (int ii = 0; ii < 8; ++ii) o[ii] = tile[sc * 8 + ii][d];
        *(u16x8*)&Vt[(size_t)n * DH * S_LEN + (size_t)d * S_LEN + s0 + sc * 8] = o;
    }
}

// ---------------- main attention kernel (bf16 inputs) ------------------
__global__ __launch_bounds__(256) void sdpa_bf16(
        const unsigned short* __restrict__ Qb, const unsigned short* __restrict__ Kb,
        const unsigned short* __restrict__ Vtb, float* __restrict__ O)
{
    __shared__ __attribute__((aligned(16))) unsigned short Kl[2][BK * DH];
    __shared__ __attribute__((aligned(16))) unsigned short Vl[2][BK * DH];
    __shared__ __attribute__((aligned(16))) unsigned short Pl[4][16 * BK];

    const int tid = threadIdx.x;
    const int w   = tid >> 6;
    const int ln  = tid & 63;
    const int lg  = ln >> 4;
    const int lr  = ln & 15;

    // XCD swizzle: 1024 blocks, 128 per XCD -> each XCD sees only 4 heads' K/V
    const int b2 = (blockIdx.x & 7) * 128 + (blockIdx.x >> 3);
    const int n  = b2 >> 5;
    const int qt = b2 & 31;
    const int q0 = qt * BM + w * 16;

    const size_t hoff = (size_t)n * S_LEN * DH;
    const unsigned short* __restrict__ Qh  = Qb  + hoff;
    const unsigned short* __restrict__ Kh  = Kb  + hoff;
    const unsigned short* __restrict__ Vth = Vtb + hoff;
    float* __restrict__ Oh = O + hoff;

    // Q fragments (already scaled+bf16)
    s16x8 qf[2];
    #pragma unroll
    for (int t = 0; t < 2; ++t)
        qf[t] = *(const s16x8*)(Qh + (size_t)(q0 + lr) * DH + t * 32 + lg * 8);

    float mrow[4] = {-INFINITY, -INFINITY, -INFINITY, -INFINITY};
    float lrow[4] = {0.f, 0.f, 0.f, 0.f};
    f32x4 oacc[4];
    #pragma unroll
    for (int nn = 0; nn < 4; ++nn) oacc[nn] = (f32x4){0.f, 0.f, 0.f, 0.f};

    // stage one K/V tile: global_load_lds, LDS linear, source pre-swizzled
    auto stage = [&](int buf, int k0) {
        #pragma unroll
        for (int pass = 0; pass < 2; ++pass) {
            const int s    = pass * 256 + w * 64 + ln;   // 16B-chunk id 0..511
            const int row  = s >> 3;
            const int c    = s & 7;
            const int csrc = c ^ (row & 7);
            const unsigned short* gk = Kh + (size_t)(k0 + row) * DH + csrc * 8;
            __builtin_amdgcn_global_load_lds((gas_ptr)gk,
                    (las_ptr)&Kl[buf][(pass * 256 + w * 64) * 8], 16, 0, 0);
            const unsigned short* gv = Vth + (size_t)row * S_LEN + k0 + csrc * 8;
            __builtin_amdgcn_global_load_lds((gas_ptr)gv,
                    (las_ptr)&Vl[buf][(pass * 256 + w * 64) * 8], 16, 0, 0);
        }
    };

    stage(0, 0);
    __syncthreads();
    int cur = 0;

    for (int it = 0; it < NTILE; ++it) {
        if (it + 1 < NTILE) stage(cur ^ 1, (it + 1) * BK);   // prefetch overlaps compute

        // ---- S = Q K^T
        f32x4 sacc[4];
        __builtin_amdgcn_s_setprio(1);
        #pragma unroll
        for (int kt = 0; kt < 4; ++kt) {
            f32x4 acc = (f32x4){0.f, 0.f, 0.f, 0.f};
            #pragma unroll
            for (int t = 0; t < 2; ++t) {
                s16x8 kf = *(const s16x8*)&Kl[cur][swz(kt * 16 + lr, t * 32 + lg * 8)];
                acc = __builtin_amdgcn_mfma_f32_16x16x32_bf16(
                        __builtin_bit_cast(bf16x8, qf[t]),
                        __builtin_bit_cast(bf16x8, kf), acc, 0, 0, 0);
            }
            sacc[kt] = acc;
        }
        __builtin_amdgcn_s_setprio(0);

        // ---- online softmax
        float alpha[4];
        #pragma unroll
        for (int j = 0; j < 4; ++j) {
            float v = fmaxf(fmaxf(sacc[0][j], sacc[1][j]),
                            fmaxf(sacc[2][j], sacc[3][j]));
            #pragma unroll
            for (int off = 1; off < 16; off <<= 1) v = fmaxf(v, __shfl_xor(v, off));
            const float mn = fmaxf(mrow[j], v);
            alpha[j] = __expf(mrow[j] - mn);
            mrow[j] = mn;
        }
        float psum[4] = {0.f, 0.f, 0.f, 0.f};
        #pragma unroll
        for (int kt = 0; kt < 4; ++kt) {
            #pragma unroll
            for (int j = 0; j < 4; ++j) {
                const float p = __expf(sacc[kt][j] - mrow[j]);
                const unsigned short pb = f2bf(p);
                psum[j] += bf2f(pb);
                Pl[w][swz(lg * 4 + j, kt * 16 + lr)] = pb;
            }
        }
        #pragma unroll
        for (int j = 0; j < 4; ++j) {
            float s = psum[j];
            #pragma unroll
            for (int off = 1; off < 16; off <<= 1) s += __shfl_xor(s, off);
            lrow[j] = lrow[j] * alpha[j] + s;
        }
        #pragma unroll
        for (int nn = 0; nn < 4; ++nn) {
            #pragma unroll
            for (int j = 0; j < 4; ++j) oacc[nn][j] *= alpha[j];
        }

        // ---- O += P V
        __builtin_amdgcn_s_setprio(1);
        #pragma unroll
        for (int t = 0; t < 2; ++t) {
            s16x8 pf = *(const s16x8*)&Pl[w][swz(lr, t * 32 + lg * 8)];
            #pragma unroll
            for (int nn = 0; nn < 4; ++nn) {
                s16x8 vf = *(const s16x8*)&Vl[cur][swz(nn * 16 + lr, t * 32 + lg * 8)];
                oacc[nn] = __builtin_amdgcn_mfma_f32_16x16x32_bf16(
                        __builtin_bit_cast(bf16x8, pf),
                        __builtin_bit_cast(bf16x8, vf), oacc[nn], 0, 0, 0);
            }
        }
        __builtin_amdgcn_s_setprio(0);

        __syncthreads();   // drains vmcnt (prefetch) + lgkm; buffers swap
        cur ^= 1;
    }

    #pragma unroll
    for (int j = 0; j < 4; ++j) {
        const float inv = 1.0f / lrow[j];
        #pragma unroll
        for (int nn = 0; nn < 4; ++nn)
            Oh[(size_t)(q0 + lg * 4 + j) * DH + nn * 16 + lr] = oacc[nn][j] * inv;
    }
}

// ---------------- round-1 fallback (fp32 in, self-staging) -------------
__global__ __launch_bounds__(256) void sdpa_fwd_fb(
        const float* __restrict__ Q, const float* __restrict__ K,
        const float* __restrict__ V, float* __restrict__ O)
{
    __shared__ __attribute__((aligned(16))) unsigned short Klf[BK * DH];
    __shared__ __attribute__((aligned(16))) unsigned short Vtf[DH * BK];
    __shared__ __attribute__((aligned(16))) unsigned short Plf[4][16 * BK];

    const int tid = threadIdx.x;
    const int w = tid >> 6, ln = tid & 63, lg = ln >> 4, lr = ln & 15;
    const int n = blockIdx.x >> 5, qt = blockIdx.x & 31;
    const int q0 = qt * BM + w * 16;
    const size_t hoff = (size_t)n * S_LEN * DH;
    const float *Qh = Q + hoff, *Kh = K + hoff, *Vh = V + hoff;
    float* Oh = O + hoff;

    s16x8 qf[2];
    #pragma unroll
    for (int t = 0; t < 2; ++t) {
        const float* src = Qh + (size_t)(q0 + lr) * DH + t * 32 + lg * 8;
        float4 a = *(const float4*)(src);
        float4 b = *(const float4*)(src + 4);
        s16x8 v;
        v[0] = (short)f2bf(a.x * 0.125f); v[1] = (short)f2bf(a.y * 0.125f);
        v[2] = (short)f2bf(a.z * 0.125f); v[3] = (short)f2bf(a.w * 0.125f);
        v[4] = (short)f2bf(b.x * 0.125f); v[5] = (short)f2bf(b.y * 0.125f);
        v[6] = (short)f2bf(b.z * 0.125f); v[7] = (short)f2bf(b.w * 0.125f);
        qf[t] = v;
    }
    float mrow[4] = {-INFINITY, -INFINITY, -INFINITY, -INFINITY};
    float lrow[4] = {0.f, 0.f, 0.f, 0.f};
    f32x4 oacc[4];
    #pragma unroll
    for (int nn = 0; nn < 4; ++nn) oacc[nn] = (f32x4){0.f, 0.f, 0.f, 0.f};

    for (int it = 0; it < NTILE; ++it) {
        const int k0 = it * BK;
        __syncthreads();
        #pragma unroll
        for (int r4 = 0; r4 < 4; ++r4) {
            const int lin = tid + 256 * r4;
            const int row = lin >> 4, c4 = lin & 15;
            float4 kv = *(const float4*)(Kh + (size_t)(k0 + row) * DH + c4 * 4);
            u16x4 kb;
            kb[0] = f2bf(kv.x); kb[1] = f2bf(kv.y); kb[2] = f2bf(kv.z); kb[3] = f2bf(kv.w);
            *(u16x4*)&Klf[swz(row, c4 * 4)] = kb;
            float4 vv = *(const float4*)(Vh + (size_t)(k0 + row) * DH + c4 * 4);
            const float vals[4] = {vv.x, vv.y, vv.z, vv.w};
            #pragma unroll
            for (int ii = 0; ii < 4; ++ii) Vtf[swz(c4 * 4 + ii, row)] = f2bf(vals[ii]);
        }
        __syncthreads();
        f32x4 sacc[4];
        #pragma unroll
        for (int kt = 0; kt < 4; ++kt) {
            f32x4 acc = (f32x4){0.f, 0.f, 0.f, 0.f};
            #pragma unroll
            for (int t = 0; t < 2; ++t) {
                s16x8 kf = *(const s16x8*)&Klf[swz(kt * 16 + lr, t * 32 + lg * 8)];
                acc = __builtin_amdgcn_mfma_f32_16x16x32_bf16(
                        __builtin_bit_cast(bf16x8, qf[t]),
                        __builtin_bit_cast(bf16x8, kf), acc, 0, 0, 0);
            }
            sacc[kt] = acc;
        }
        float alpha[4];
        #pragma unroll
        for (int j = 0; j < 4; ++j) {
            float v = fmaxf(fmaxf(sacc[0][j], sacc[1][j]), fmaxf(sacc[2][j], sacc[3][j]));
            #pragma unroll
            for (int off = 1; off < 16; off <<= 1) v = fmaxf(v, __shfl_xor(v, off));
            const float mn = fmaxf(mrow[j], v);
            alpha[j] = __expf(mrow[j] - mn);
            mrow[j] = mn;
        }
        float psum[4] = {0.f, 0.f, 0.f, 0.f};
        #pragma unroll
        for (int kt = 0; kt < 4; ++kt) {
            #pragma unroll
            for (int j = 0; j < 4; ++j) {
                const float p = __expf(sacc[kt][j] - mrow[j]);
                const unsigned short pb = f2bf(p);
                psum[j] += bf2f(pb);
                Plf[w][swz(lg * 4 + j, kt * 16 + lr)] = pb;
            }
        }
        #pragma unroll
        for (int j = 0; j < 4; ++j) {
            float s = psum[j];
            #pragma unroll
            for (int off = 1; off < 16; off <<= 1) s += __shfl_xor(s, off);
            lrow[j] = lrow[j] * alpha[j] + s;
        }
        #pragma unroll
        for (int nn = 0; nn < 4; ++nn) {
            #pragma unroll
            for (int j = 0; j < 4; ++j) oacc[nn][j] *= alpha[j];
        }
        #pragma unroll
        for (int t = 0; t < 2; ++t) {
            s16x8 pf = *(const s16x8*)&Plf[w][swz(lr, t * 32 + lg * 8)];
            #pragma unroll
            for (int nn = 0; nn < 4; ++nn) {
                s16x8 vf = *(const s16x8*)&Vtf[swz(nn * 16 + lr, t * 32 + lg * 8)];
                oacc[nn] = __builtin_amdgcn_mfma_f32_16x16x32_bf16(
                        __builtin_bit_cast(bf16x8, pf),
                        __builtin_bit_cast(bf16x8, vf), oacc[nn], 0, 0, 0);
            }
        }
    }
    #pragma unroll
    for (int j = 0; j < 4; ++j) {
        const float inv = 1.0f / lrow[j];
        #pragma unroll
        for (int nn = 0; nn < 4; ++nn)
            Oh[(size_t)(q0 + lg * 4 + j) * DH + nn * 16 + lr] = oacc[nn][j] * inv;
    }
}

extern "C" void kernel_launch(void* const* d_in, const int* in_sizes, int n_in,
                              void* d_out, int out_size, void* d_ws, size_t ws_size,
                              hipStream_t stream) {
    const float* Q = (const float*)d_in[0];
    const float* K = (const float*)d_in[1];
    const float* V = (const float*)d_in[2];
    float* O = (float*)d_out;

    const size_t elems = (size_t)NH * S_LEN * DH;        // 4.19M
    const size_t bf_bytes = elems * 2;                   // 8 MB per tensor
    if (ws_size >= 3 * bf_bytes) {
        unsigned short* Qb  = (unsigned short*)d_ws;
        unsigned short* Kb  = Qb + elems;
        unsigned short* Vtb = Kb + elems;
        const int n8 = (int)(elems / 8);
        conv_qk<<<(n8 + 255) / 256, 256, 0, stream>>>(Q, K, Qb, Kb, n8);
        conv_vt<<<NH * (S_LEN / 64), 256, 0, stream>>>(V, Vtb);
        sdpa_bf16<<<NH * (S_LEN / BM), 256, 0, stream>>>(Qb, Kb, Vtb, O);
    } else {
        sdpa_fwd_fb<<<NH * (S_LEN / BM), 256, 0, stream>>>(Q, K, V, O);
    }
}

// Round 4
// 72.948 us; speedup vs baseline: 2.5250x; 1.7205x over previous
//
#include <hip/hip_runtime.h>
#include <cstdint>
#include <cstddef>

typedef __bf16 bf16x8 __attribute__((ext_vector_type(8)));
typedef float f32x4 __attribute__((ext_vector_type(4)));
typedef float f32x16 __attribute__((ext_vector_type(16)));
typedef short s16x8 __attribute__((ext_vector_type(8)));
typedef unsigned short u16x4 __attribute__((ext_vector_type(4)));
typedef unsigned short u16x8 __attribute__((ext_vector_type(8)));
typedef int i32x4 __attribute__((ext_vector_type(4)));

#define S_LEN 2048
#define DH    64
#define BK    64
#define NTILE (S_LEN / BK)
#define NH    32
#define QBLK  128          // q-rows per block (4 waves x 32)

#if __has_builtin(__builtin_amdgcn_exp2f)
#define EXPF(x) __builtin_amdgcn_exp2f(x)
#define QSCALE 0.18033688011112043f   /* 0.125 * log2(e) */
#else
#define EXPF(x) __expf(x)
#define QSCALE 0.125f
#endif

typedef const __attribute__((address_space(1))) void* gas_ptr;
typedef __attribute__((address_space(3))) void* las_ptr;

static __device__ __forceinline__ unsigned short f2bf(float x) {
    unsigned int u = __builtin_bit_cast(unsigned int, x);
    u += 0x7FFFu + ((u >> 16) & 1u);   // RNE
    return (unsigned short)(u >> 16);
}

// swizzled ushort index inside a [rows][64] bf16 LDS tile
static __device__ __forceinline__ int swz(int row, int col) {
    return row * 64 + (col ^ ((row & 7) << 3));
}

static __device__ __forceinline__ unsigned cvtpk(float lo, float hi) {
    unsigned r;
    asm("v_cvt_pk_bf16_f32 %0, %1, %2" : "=v"(r) : "v"(lo), "v"(hi));
    return r;
}

// v_permlane32_swap direction (b): new_x[32+i] = old_y[i]; new_y[i] = old_x[32+i]
// (UPPER half of x swaps with LOWER half of y). This is the direction
// consistent with the verified m214 T12 recipe; round-3's (a) was backwards.
static __device__ __forceinline__ void swap32(int& x, int& y, int hi) {
#if __has_builtin(__builtin_amdgcn_permlane32_swap)
    (void)hi;
    auto r = __builtin_amdgcn_permlane32_swap(x, y, false, false);
    x = r[0]; y = r[1];
#else
    int px = __shfl_xor(x, 32), py = __shfl_xor(y, 32);
    int nx = hi ? py : x;   // upper lanes receive partner's y
    int ny = hi ? y  : px;  // lower lanes receive partner's x
    x = nx; y = ny;
#endif
}

// Build one PV B-fragment (16 contraction elems) from 4 packed-bf16 words:
// lo0/lo1 = lane's keys (base+0,1)/(base+2,3); up0/up1 = keys (base+8..11)
// group. After swap32: dword0=lo0, dword1=lo1, dword2=up0, dword3=up1 holds
// keys [hi*8 .. hi*8+7] of the 16-chunk in both lane halves.
static __device__ __forceinline__ bf16x8 mkfrag(int lo0, int lo1, int up0, int up1, int hi) {
    swap32(lo0, up0, hi);
    swap32(lo1, up1, hi);
    i32x4 f = {lo0, lo1, up0, up1};
    return __builtin_bit_cast(bf16x8, f);
}

// ---------------- pre-pass: fp32 -> bf16 (Q scaled), K ----------------
__global__ __launch_bounds__(256) void conv_qk(
        const float* __restrict__ Q, const float* __restrict__ K,
        unsigned short* __restrict__ Qb, unsigned short* __restrict__ Kb, int n8)
{
    const int i = blockIdx.x * 256 + threadIdx.x;
    if (i >= n8) return;
    {
        float4 a = ((const float4*)Q)[2 * i], b = ((const float4*)Q)[2 * i + 1];
        u16x8 o;
        o[0] = f2bf(a.x * QSCALE); o[1] = f2bf(a.y * QSCALE);
        o[2] = f2bf(a.z * QSCALE); o[3] = f2bf(a.w * QSCALE);
        o[4] = f2bf(b.x * QSCALE); o[5] = f2bf(b.y * QSCALE);
        o[6] = f2bf(b.z * QSCALE); o[7] = f2bf(b.w * QSCALE);
        *(u16x8*)&Qb[(size_t)i * 8] = o;
    }
    {
        float4 a = ((const float4*)K)[2 * i], b = ((const float4*)K)[2 * i + 1];
        u16x8 o;
        o[0] = f2bf(a.x); o[1] = f2bf(a.y); o[2] = f2bf(a.z); o[3] = f2bf(a.w);
        o[4] = f2bf(b.x); o[5] = f2bf(b.y); o[6] = f2bf(b.z); o[7] = f2bf(b.w);
        *(u16x8*)&Kb[(size_t)i * 8] = o;
    }
}

// ---------------- pre-pass: V -> V^T bf16 per head --------------------
__global__ __launch_bounds__(256) void conv_vt(
        const float* __restrict__ V, unsigned short* __restrict__ Vt)
{
    __shared__ unsigned short tile[64][72];
    const int tid = threadIdx.x;
    const int n  = blockIdx.x >> 5;
    const int s0 = (blockIdx.x & 31) * 64;
    const float* Vh = V + (size_t)n * S_LEN * DH + (size_t)s0 * DH;

    #pragma unroll
    for (int r4 = 0; r4 < 4; ++r4) {
        const int lin = tid + 256 * r4;
        const int row = lin >> 4;
        const int c4  = lin & 15;
        float4 v = *(const float4*)(Vh + (size_t)row * DH + c4 * 4);
        u16x4 b;
        b[0] = f2bf(v.x); b[1] = f2bf(v.y); b[2] = f2bf(v.z); b[3] = f2bf(v.w);
        *(u16x4*)&tile[row][c4 * 4] = b;
    }
    __syncthreads();
    #pragma unroll
    for (int p = 0; p < 2; ++p) {
        const int cid = tid + 256 * p;
        const int d  = cid >> 3;
        const int sc = cid & 7;
        u16x8 o;
        #pragma unroll
        for (int ii = 0; ii < 8; ++ii) o[ii] = tile[sc * 8 + ii][d];
        *(u16x8*)&Vt[(size_t)n * DH * S_LEN + (size_t)d * S_LEN + s0 + sc * 8] = o;
    }
}

// ---------------- main: 32x32 swapped-QK^T flash attention -------------
__global__ __launch_bounds__(256) void sdpa32(
        const unsigned short* __restrict__ Qb, const unsigned short* __restrict__ Kb,
        const unsigned short* __restrict__ Vtb, float* __restrict__ O)
{
    __shared__ __attribute__((aligned(16))) unsigned short Kl[2][BK * DH];
    __shared__ __attribute__((aligned(16))) unsigned short Vl[2][BK * DH];

    const int tid = threadIdx.x;
    const int w   = tid >> 6;
    const int ln  = tid & 63;
    const int r31 = ln & 31;
    const int hi  = ln >> 5;

    // XCD swizzle: 512 blocks -> 64 per XCD (4 heads/XCD: K/V 2MB, L2-fits)
    const int b2 = (blockIdx.x & 7) * 64 + (blockIdx.x >> 3);
    const int n  = b2 >> 4;
    const int qt = b2 & 15;
    const int q0 = qt * QBLK + w * 32;

    const size_t hoff = (size_t)n * S_LEN * DH;
    const unsigned short* __restrict__ Qh  = Qb  + hoff;
    const unsigned short* __restrict__ Kh  = Kb  + hoff;
    const unsigned short* __restrict__ Vth = Vtb + hoff;
    float* __restrict__ Oh = O + hoff;

    // Q B-fragments: lane holds Q[q0+r31][dsub*16 + hi*8 + e]
    s16x8 qf[4];
    #pragma unroll
    for (int dsub = 0; dsub < 4; ++dsub)
        qf[dsub] = *(const s16x8*)(Qh + (size_t)(q0 + r31) * DH + dsub * 16 + hi * 8);

    float m = -INFINITY, l = 0.f;
    f32x16 oacc0 = {}, oacc1 = {};

    auto stage = [&](int buf, int k0) {
        #pragma unroll
        for (int pass = 0; pass < 2; ++pass) {
            const int s    = pass * 256 + w * 64 + ln;
            const int row  = s >> 3;
            const int c    = s & 7;
            const int csrc = c ^ (row & 7);
            const unsigned short* gk = Kh + (size_t)(k0 + row) * DH + csrc * 8;
            __builtin_amdgcn_global_load_lds((gas_ptr)gk,
                    (las_ptr)&Kl[buf][(pass * 256 + w * 64) * 8], 16, 0, 0);
            const unsigned short* gv = Vth + (size_t)row * S_LEN + k0 + csrc * 8;
            __builtin_amdgcn_global_load_lds((gas_ptr)gv,
                    (las_ptr)&Vl[buf][(pass * 256 + w * 64) * 8], 16, 0, 0);
        }
    };

    stage(0, 0);
    __syncthreads();
    int cur = 0;

    for (int it = 0; it < NTILE; ++it) {
        if (it + 1 < NTILE) stage(cur ^ 1, (it + 1) * BK);

        // ---- S^T = K Q^T : two 32-key subtiles, D=64 as 4 K-chunks of 16
        f32x16 s0 = {}, s1 = {};
        __builtin_amdgcn_s_setprio(1);
        #pragma unroll
        for (int dsub = 0; dsub < 4; ++dsub) {
            s16x8 kf0 = *(const s16x8*)&Kl[cur][swz(r31,      (dsub * 2 + hi) * 8)];
            s16x8 kf1 = *(const s16x8*)&Kl[cur][swz(32 + r31, (dsub * 2 + hi) * 8)];
            s0 = __builtin_amdgcn_mfma_f32_32x32x16_bf16(
                    __builtin_bit_cast(bf16x8, kf0),
                    __builtin_bit_cast(bf16x8, qf[dsub]), s0, 0, 0, 0);
            s1 = __builtin_amdgcn_mfma_f32_32x32x16_bf16(
                    __builtin_bit_cast(bf16x8, kf1),
                    __builtin_bit_cast(bf16x8, qf[dsub]), s1, 0, 0, 0);
        }
        __builtin_amdgcn_s_setprio(0);

        // ---- in-register online softmax (lane owns q = q0 + r31; holds 32
        //      of 64 keys, partner lane^32 the rest)
        float t[16];
        #pragma unroll
        for (int i = 0; i < 16; ++i) t[i] = fmaxf(s0[i], s1[i]);
        #pragma unroll
        for (int st = 8; st >= 1; st >>= 1)
            #pragma unroll
            for (int i = 0; i < 8; ++i)
                if (i < st) t[i] = fmaxf(t[i], t[i + st]);
        const float pmax = fmaxf(t[0], __shfl_xor(t[0], 32));

        if (!__all(pmax - m <= 8.0f)) {      // defer-max (T13)
            const float mn = fmaxf(m, pmax);
            const float al = EXPF(m - mn);
            m = mn;
            l *= al;
            #pragma unroll
            for (int i = 0; i < 16; ++i) { oacc0[i] *= al; oacc1[i] *= al; }
        }

        float p0[16], p1[16];
        #pragma unroll
        for (int i = 0; i < 16; ++i) {
            p0[i] = EXPF(s0[i] - m);
            p1[i] = EXPF(s1[i] - m);
        }
        {
            float su[16];
            #pragma unroll
            for (int i = 0; i < 16; ++i) su[i] = p0[i] + p1[i];
            #pragma unroll
            for (int st = 8; st >= 1; st >>= 1)
                #pragma unroll
                for (int i = 0; i < 8; ++i)
                    if (i < st) su[i] += su[i + st];
            l += su[0];
        }

        // ---- P^T -> bf16 B-fragments in-register (T12)
        // wa[i] = keys (crow(2i,hi), crow(2i+1,hi)) of s0; wb same for s1.
        unsigned wa[8], wb[8];
        #pragma unroll
        for (int i = 0; i < 8; ++i) {
            wa[i] = cvtpk(p0[2 * i], p0[2 * i + 1]);
            wb[i] = cvtpk(p1[2 * i], p1[2 * i + 1]);
        }
        bf16x8 pf[4];
        pf[0] = mkfrag(wa[0], wa[1], wa[2], wa[3], hi);   // keys  0..15
        pf[1] = mkfrag(wa[4], wa[5], wa[6], wa[7], hi);   // keys 16..31
        pf[2] = mkfrag(wb[0], wb[1], wb[2], wb[3], hi);   // keys 32..47
        pf[3] = mkfrag(wb[4], wb[5], wb[6], wb[7], hi);   // keys 48..63

        // ---- O^T += V^T P^T : 64 keys as 4 K-chunks of 16, D as 2 M-tiles
        __builtin_amdgcn_s_setprio(1);
        #pragma unroll
        for (int ks = 0; ks < 4; ++ks) {
            s16x8 vf0 = *(const s16x8*)&Vl[cur][swz(r31,      (ks * 2 + hi) * 8)];
            s16x8 vf1 = *(const s16x8*)&Vl[cur][swz(32 + r31, (ks * 2 + hi) * 8)];
            oacc0 = __builtin_amdgcn_mfma_f32_32x32x16_bf16(
                    __builtin_bit_cast(bf16x8, vf0), pf[ks], oacc0, 0, 0, 0);
            oacc1 = __builtin_amdgcn_mfma_f32_32x32x16_bf16(
                    __builtin_bit_cast(bf16x8, vf1), pf[ks], oacc1, 0, 0, 0);
        }
        __builtin_amdgcn_s_setprio(0);

        __syncthreads();   // drains prefetch vmcnt; all waves done with cur
        cur ^= 1;
    }

    // ---- epilogue: combine partner-lane denominators, normalize, store
    const float lt  = l + __shfl_xor(l, 32);
    const float inv = 1.0f / lt;
    float* Orow = Oh + (size_t)(q0 + r31) * DH;
    #pragma unroll
    for (int g = 0; g < 4; ++g) {
        float4 o0 = { oacc0[4*g] * inv, oacc0[4*g+1] * inv,
                      oacc0[4*g+2] * inv, oacc0[4*g+3] * inv };
        *(float4*)&Orow[g * 8 + hi * 4] = o0;
        float4 o1 = { oacc1[4*g] * inv, oacc1[4*g+1] * inv,
                      oacc1[4*g+2] * inv, oacc1[4*g+3] * inv };
        *(float4*)&Orow[32 + g * 8 + hi * 4] = o1;
    }
}

// ---------------- fallback (fp32 in, self-staging, round-1 proven) ------
__global__ __launch_bounds__(256) void sdpa_fwd_fb(
        const float* __restrict__ Q, const float* __restrict__ K,
        const float* __restrict__ V, float* __restrict__ O)
{
    __shared__ __attribute__((aligned(16))) unsigned short Klf[BK * DH];
    __shared__ __attribute__((aligned(16))) unsigned short Vtf[DH * BK];
    __shared__ __attribute__((aligned(16))) unsigned short Plf[4][16 * BK];

    const int tid = threadIdx.x;
    const int w = tid >> 6, ln = tid & 63, lg = ln >> 4, lr = ln & 15;
    const int n = blockIdx.x >> 5, qt = blockIdx.x & 31;
    const int q0 = qt * 64 + w * 16;
    const size_t hoff = (size_t)n * S_LEN * DH;
    const float *Qh = Q + hoff, *Kh = K + hoff, *Vh = V + hoff;
    float* Oh = O + hoff;

    s16x8 qf[2];
    #pragma unroll
    for (int t = 0; t < 2; ++t) {
        const float* src = Qh + (size_t)(q0 + lr) * DH + t * 32 + lg * 8;
        float4 a = *(const float4*)(src);
        float4 b = *(const float4*)(src + 4);
        s16x8 v;
        v[0] = (short)f2bf(a.x * 0.125f); v[1] = (short)f2bf(a.y * 0.125f);
        v[2] = (short)f2bf(a.z * 0.125f); v[3] = (short)f2bf(a.w * 0.125f);
        v[4] = (short)f2bf(b.x * 0.125f); v[5] = (short)f2bf(b.y * 0.125f);
        v[6] = (short)f2bf(b.z * 0.125f); v[7] = (short)f2bf(b.w * 0.125f);
        qf[t] = v;
    }
    float mrow[4] = {-INFINITY, -INFINITY, -INFINITY, -INFINITY};
    float lrow[4] = {0.f, 0.f, 0.f, 0.f};
    f32x4 oacc[4];
    #pragma unroll
    for (int nn = 0; nn < 4; ++nn) oacc[nn] = (f32x4){0.f, 0.f, 0.f, 0.f};

    for (int it = 0; it < NTILE; ++it) {
        const int k0 = it * BK;
        __syncthreads();
        #pragma unroll
        for (int r4 = 0; r4 < 4; ++r4) {
            const int lin = tid + 256 * r4;
            const int row = lin >> 4, c4 = lin & 15;
            float4 kv = *(const float4*)(Kh + (size_t)(k0 + row) * DH + c4 * 4);
            u16x4 kb;
            kb[0] = f2bf(kv.x); kb[1] = f2bf(kv.y); kb[2] = f2bf(kv.z); kb[3] = f2bf(kv.w);
            *(u16x4*)&Klf[swz(row, c4 * 4)] = kb;
            float4 vv = *(const float4*)(Vh + (size_t)(k0 + row) * DH + c4 * 4);
            const float vals[4] = {vv.x, vv.y, vv.z, vv.w};
            #pragma unroll
            for (int ii = 0; ii < 4; ++ii) Vtf[swz(c4 * 4 + ii, row)] = f2bf(vals[ii]);
        }
        __syncthreads();
        f32x4 sacc[4];
        #pragma unroll
        for (int kt = 0; kt < 4; ++kt) {
            f32x4 acc = (f32x4){0.f, 0.f, 0.f, 0.f};
            #pragma unroll
            for (int t = 0; t < 2; ++t) {
                s16x8 kf = *(const s16x8*)&Klf[swz(kt * 16 + lr, t * 32 + lg * 8)];
                acc = __builtin_amdgcn_mfma_f32_16x16x32_bf16(
                        __builtin_bit_cast(bf16x8, qf[t]),
                        __builtin_bit_cast(bf16x8, kf), acc, 0, 0, 0);
            }
            sacc[kt] = acc;
        }
        float alpha[4];
        #pragma unroll
        for (int j = 0; j < 4; ++j) {
            float v = fmaxf(fmaxf(sacc[0][j], sacc[1][j]), fmaxf(sacc[2][j], sacc[3][j]));
            #pragma unroll
            for (int off = 1; off < 16; off <<= 1) v = fmaxf(v, __shfl_xor(v, off));
            const float mn = fmaxf(mrow[j], v);
            alpha[j] = __expf(mrow[j] - mn);
            mrow[j] = mn;
        }
        float psum[4] = {0.f, 0.f, 0.f, 0.f};
        #pragma unroll
        for (int kt = 0; kt < 4; ++kt) {
            #pragma unroll
            for (int j = 0; j < 4; ++j) {
                const float p = __expf(sacc[kt][j] - mrow[j]);
                const unsigned short pb = f2bf(p);
                unsigned int pu = ((unsigned int)pb) << 16;
                psum[j] += __builtin_bit_cast(float, pu);
                Plf[w][swz(lg * 4 + j, kt * 16 + lr)] = pb;
            }
        }
        #pragma unroll
        for (int j = 0; j < 4; ++j) {
            float s = psum[j];
            #pragma unroll
            for (int off = 1; off < 16; off <<= 1) s += __shfl_xor(s, off);
            lrow[j] = lrow[j] * alpha[j] + s;
        }
        #pragma unroll
        for (int nn = 0; nn < 4; ++nn) {
            #pragma unroll
            for (int j = 0; j < 4; ++j) oacc[nn][j] *= alpha[j];
        }
        #pragma unroll
        for (int t = 0; t < 2; ++t) {
            s16x8 pf = *(const s16x8*)&Plf[w][swz(lr, t * 32 + lg * 8)];
            #pragma unroll
            for (int nn = 0; nn < 4; ++nn) {
                s16x8 vf = *(const s16x8*)&Vtf[swz(nn * 16 + lr, t * 32 + lg * 8)];
                oacc[nn] = __builtin_amdgcn_mfma_f32_16x16x32_bf16(
                        __builtin_bit_cast(bf16x8, pf),
                        __builtin_bit_cast(bf16x8, vf), oacc[nn], 0, 0, 0);
            }
        }
    }
    #pragma unroll
    for (int j = 0; j < 4; ++j) {
        const float inv = 1.0f / lrow[j];
        #pragma unroll
        for (int nn = 0; nn < 4; ++nn)
            Oh[(size_t)(q0 + lg * 4 + j) * DH + nn * 16 + lr] = oacc[nn][j] * inv;
    }
}

extern "C" void kernel_launch(void* const* d_in, const int* in_sizes, int n_in,
                              void* d_out, int out_size, void* d_ws, size_t ws_size,
                              hipStream_t stream) {
    const float* Q = (const float*)d_in[0];
    const float* K = (const float*)d_in[1];
    const float* V = (const float*)d_in[2];
    float* O = (float*)d_out;

    const size_t elems = (size_t)NH * S_LEN * DH;
    const size_t bf_bytes = elems * 2;
    if (ws_size >= 3 * bf_bytes) {
        unsigned short* Qbf = (unsigned short*)d_ws;
        unsigned short* Kbf = Qbf + elems;
        unsigned short* Vtb = Kbf + elems;
        const int n8 = (int)(elems / 8);
        conv_qk<<<(n8 + 255) / 256, 256, 0, stream>>>(Q, K, Qbf, Kbf, n8);
        conv_vt<<<NH * (S_LEN / 64), 256, 0, stream>>>(V, Vtb);
        sdpa32<<<NH * (S_LEN / QBLK), 256, 0, stream>>>(Qbf, Kbf, Vtb, O);
    } else {
        sdpa_fwd_fb<<<NH * (S_LEN / 64), 256, 0, stream>>>(Q, K, V, O);
    }
}

// Round 5
// 67.881 us; speedup vs baseline: 2.7135x; 1.0746x over previous
//
#include <hip/hip_runtime.h>
#include <cstdint>
#include <cstddef>

typedef __bf16 bf16x8 __attribute__((ext_vector_type(8)));
typedef float f32x4 __attribute__((ext_vector_type(4)));
typedef float f32x16 __attribute__((ext_vector_type(16)));
typedef short s16x8 __attribute__((ext_vector_type(8)));
typedef unsigned short u16x4 __attribute__((ext_vector_type(4)));
typedef unsigned short u16x8 __attribute__((ext_vector_type(8)));
typedef int i32x4 __attribute__((ext_vector_type(4)));

#define S_LEN 2048
#define DH    64
#define BK    64
#define NTILE (S_LEN / BK)
#define NH    32
#define QBLK  128          // q-rows per block (4 waves x 32)

#if __has_builtin(__builtin_amdgcn_exp2f)
#define EXPF(x) __builtin_amdgcn_exp2f(x)
#define QSCALE 0.18033688011112043f   /* 0.125 * log2(e) */
#else
#define EXPF(x) __expf(x)
#define QSCALE 0.125f
#endif

typedef const __attribute__((address_space(1))) void* gas_ptr;
typedef __attribute__((address_space(3))) void* las_ptr;

static __device__ __forceinline__ unsigned short f2bf(float x) {
    unsigned int u = __builtin_bit_cast(unsigned int, x);
    u += 0x7FFFu + ((u >> 16) & 1u);   // RNE
    return (unsigned short)(u >> 16);
}

static __device__ __forceinline__ unsigned cvtpk(float lo, float hi) {
    unsigned r;
    asm("v_cvt_pk_bf16_f32 %0, %1, %2" : "=v"(r) : "v"(lo), "v"(hi));
    return r;
}

// v_permlane32_swap direction (b): upper half of x <-> lower half of y.
static __device__ __forceinline__ void swap32(int& x, int& y, int hi) {
#if __has_builtin(__builtin_amdgcn_permlane32_swap)
    (void)hi;
    auto r = __builtin_amdgcn_permlane32_swap(x, y, false, false);
    x = r[0]; y = r[1];
#else
    int px = __shfl_xor(x, 32), py = __shfl_xor(y, 32);
    int nx = hi ? py : x;
    int ny = hi ? y  : px;
    x = nx; y = ny;
#endif
}

static __device__ __forceinline__ bf16x8 mkfrag(int lo0, int lo1, int up0, int up1, int hi) {
    swap32(lo0, up0, hi);
    swap32(lo1, up1, hi);
    i32x4 f = {lo0, lo1, up0, up1};
    return __builtin_bit_cast(bf16x8, f);
}

// =====================================================================
// Pre-pass: one block per (head, 64-row stripe). Emits FRAGMENT-ORDERED
// bf16 chunks so the main kernel's staging is an identity copy and all
// ds_read_b128 are lane-sequential (conflict-free, immediate-offset).
//
//   Qf chunk id (per head): (qtile*4 + dsub)*64 + ln
//       content: Q[qtile*32 + (ln&31)][dsub*16 + (ln>>5)*8 + e] * QSCALE
//   Kf chunk id: (t*8 + dsub*2 + half)*64 + ln
//       content: K[t*64 + half*32 + (ln&31)][dsub*16 + (ln>>5)*8 + e]
//   Vf chunk id: (t*8 + ks*2   + half)*64 + ln
//       content: V[t*64 + ks*16 + (ln>>5)*8 + e][half*32 + (ln&31)]
// =====================================================================
__global__ __launch_bounds__(256) void prepass(
        const float* __restrict__ Q, const float* __restrict__ K,
        const float* __restrict__ V,
        unsigned short* __restrict__ Qf, unsigned short* __restrict__ Kf,
        unsigned short* __restrict__ Vf)
{
    __shared__ float Tl[64][68];   // stride 68 floats = 272B (16B-aligned)
    const int tid = threadIdx.x;
    const int head = blockIdx.x >> 5;
    const int tile = blockIdx.x & 31;

    const size_t hoff = (size_t)head * S_LEN * DH;
    const size_t soff = hoff + (size_t)tile * 64 * DH;

    // ---------- Q ----------
    #pragma unroll
    for (int p = 0; p < 4; ++p) {
        const int idx = p * 256 + tid;            // 0..1023 float4s
        const int row = idx >> 4, c4 = idx & 15;
        *(float4*)&Tl[row][c4 * 4] = *(const float4*)(Q + soff + (size_t)row * DH + c4 * 4);
    }
    __syncthreads();
    #pragma unroll
    for (int p = 0; p < 2; ++p) {
        const int cid = p * 256 + tid;            // 0..511
        const int qt_l = cid >> 8;                // 0..1
        const int dsub = (cid >> 6) & 3;
        const int ln   = cid & 63;
        const int row  = qt_l * 32 + (ln & 31);
        const int d0   = dsub * 16 + (ln >> 5) * 8;
        u16x8 o;
        #pragma unroll
        for (int e = 0; e < 8; ++e) o[e] = f2bf(Tl[row][d0 + e] * QSCALE);
        const size_t qtile = (size_t)tile * 2 + qt_l;
        *(u16x8*)&Qf[hoff + ((qtile * 4 + dsub) * 64 + ln) * 8] = o;
    }
    __syncthreads();

    // ---------- K ----------
    #pragma unroll
    for (int p = 0; p < 4; ++p) {
        const int idx = p * 256 + tid;
        const int row = idx >> 4, c4 = idx & 15;
        *(float4*)&Tl[row][c4 * 4] = *(const float4*)(K + soff + (size_t)row * DH + c4 * 4);
    }
    __syncthreads();
    #pragma unroll
    for (int p = 0; p < 2; ++p) {
        const int cid = p * 256 + tid;
        const int sub = cid >> 6;                 // 0..7 = dsub*2+half
        const int ln  = cid & 63;
        const int dsub = sub >> 1, half = sub & 1;
        const int row  = half * 32 + (ln & 31);
        const int d0   = dsub * 16 + (ln >> 5) * 8;
        u16x8 o;
        #pragma unroll
        for (int e = 0; e < 8; ++e) o[e] = f2bf(Tl[row][d0 + e]);
        *(u16x8*)&Kf[hoff + (((size_t)tile * 8 + sub) * 64 + ln) * 8] = o;
    }
    __syncthreads();

    // ---------- V (transposed into fragments) ----------
    #pragma unroll
    for (int p = 0; p < 4; ++p) {
        const int idx = p * 256 + tid;
        const int row = idx >> 4, c4 = idx & 15;
        *(float4*)&Tl[row][c4 * 4] = *(const float4*)(V + soff + (size_t)row * DH + c4 * 4);
    }
    __syncthreads();
    #pragma unroll
    for (int p = 0; p < 2; ++p) {
        const int cid = p * 256 + tid;
        const int sub = cid >> 6;                 // 0..7 = ks*2+half
        const int ln  = cid & 63;
        const int ks = sub >> 1, half = sub & 1;
        const int k0 = ks * 16 + (ln >> 5) * 8;   // key row base in stripe
        const int d  = half * 32 + (ln & 31);     // d column
        u16x8 o;
        #pragma unroll
        for (int e = 0; e < 8; ++e) o[e] = f2bf(Tl[k0 + e][d]);
        *(u16x8*)&Vf[hoff + (((size_t)tile * 8 + sub) * 64 + ln) * 8] = o;
    }
}

// =====================================================================
// Main: 32x32 swapped-QK^T flash attention over fragment-ordered inputs
// =====================================================================
__global__ __launch_bounds__(256) void sdpa32(
        const unsigned short* __restrict__ Qf, const unsigned short* __restrict__ Kf,
        const unsigned short* __restrict__ Vf, float* __restrict__ O)
{
    __shared__ __attribute__((aligned(16))) unsigned short Kl[2][512 * 8];  // 8KB/buf
    __shared__ __attribute__((aligned(16))) unsigned short Vl[2][512 * 8];

    const int tid = threadIdx.x;
    const int w   = tid >> 6;
    const int ln  = tid & 63;
    const int r31 = ln & 31;
    const int hi  = ln >> 5;

    // XCD swizzle: 512 blocks -> 64 per XCD (4 heads/XCD: K/V L2-fit)
    const int b2 = (blockIdx.x & 7) * 64 + (blockIdx.x >> 3);
    const int n  = b2 >> 4;
    const int qt = b2 & 15;
    const int q0 = qt * QBLK + w * 32;

    const size_t hoff = (size_t)n * S_LEN * DH;
    const unsigned short* __restrict__ Kh = Kf + hoff;
    const unsigned short* __restrict__ Vh = Vf + hoff;
    float* __restrict__ Oh = O + hoff;

    // Q fragments: coalesced from fragment-ordered Qf
    const int qtile = qt * 4 + w;
    s16x8 qf[4];
    #pragma unroll
    for (int dsub = 0; dsub < 4; ++dsub)
        qf[dsub] = *(const s16x8*)(Qf + hoff + (((size_t)qtile * 4 + dsub) * 64 + ln) * 8);

    float m = -INFINITY, l = 0.f;
    f32x16 oacc0 = {}, oacc1 = {};

    auto stage = [&](int buf, int t) {
        #pragma unroll
        for (int pass = 0; pass < 2; ++pass) {
            const int c = pass * 256 + w * 64;            // wave-uniform chunk base
            const unsigned short* gk = Kh + ((size_t)t * 512 + c + ln) * 8;
            __builtin_amdgcn_global_load_lds((gas_ptr)gk, (las_ptr)&Kl[buf][c * 8], 16, 0, 0);
            const unsigned short* gv = Vh + ((size_t)t * 512 + c + ln) * 8;
            __builtin_amdgcn_global_load_lds((gas_ptr)gv, (las_ptr)&Vl[buf][c * 8], 16, 0, 0);
        }
    };

    stage(0, 0);
    __syncthreads();

    auto body = [&](int it, int cur) {
        if (it + 1 < NTILE) stage(cur ^ 1, it + 1);

        // ---- S^T = K Q^T  (frag reads: lane-sequential, immediate offsets)
        f32x16 s0 = {}, s1 = {};
        __builtin_amdgcn_s_setprio(1);
        #pragma unroll
        for (int dsub = 0; dsub < 4; ++dsub) {
            s16x8 kf0 = *(const s16x8*)&Kl[cur][((dsub * 2 + 0) * 64 + ln) * 8];
            s16x8 kf1 = *(const s16x8*)&Kl[cur][((dsub * 2 + 1) * 64 + ln) * 8];
            s0 = __builtin_amdgcn_mfma_f32_32x32x16_bf16(
                    __builtin_bit_cast(bf16x8, kf0),
                    __builtin_bit_cast(bf16x8, qf[dsub]), s0, 0, 0, 0);
            s1 = __builtin_amdgcn_mfma_f32_32x32x16_bf16(
                    __builtin_bit_cast(bf16x8, kf1),
                    __builtin_bit_cast(bf16x8, qf[dsub]), s1, 0, 0, 0);
        }
        __builtin_amdgcn_s_setprio(0);

        // ---- in-register online softmax
        float t16[16];
        #pragma unroll
        for (int i = 0; i < 16; ++i) t16[i] = fmaxf(s0[i], s1[i]);
        #pragma unroll
        for (int st = 8; st >= 1; st >>= 1)
            #pragma unroll
            for (int i = 0; i < 8; ++i)
                if (i < st) t16[i] = fmaxf(t16[i], t16[i + st]);
        const float pmax = fmaxf(t16[0], __shfl_xor(t16[0], 32));

        if (!__all(pmax - m <= 8.0f)) {      // defer-max (T13)
            const float mn = fmaxf(m, pmax);
            const float al = EXPF(m - mn);
            m = mn;
            l *= al;
            #pragma unroll
            for (int i = 0; i < 16; ++i) { oacc0[i] *= al; oacc1[i] *= al; }
        }

        float p0[16], p1[16];
        #pragma unroll
        for (int i = 0; i < 16; ++i) {
            p0[i] = EXPF(s0[i] - m);
            p1[i] = EXPF(s1[i] - m);
        }
        {
            float su[16];
            #pragma unroll
            for (int i = 0; i < 16; ++i) su[i] = p0[i] + p1[i];
            #pragma unroll
            for (int st = 8; st >= 1; st >>= 1)
                #pragma unroll
                for (int i = 0; i < 8; ++i)
                    if (i < st) su[i] += su[i + st];
            l += su[0];
        }

        // ---- P^T -> bf16 B-fragments in-register (T12)
        unsigned wa[8], wb[8];
        #pragma unroll
        for (int i = 0; i < 8; ++i) {
            wa[i] = cvtpk(p0[2 * i], p0[2 * i + 1]);
            wb[i] = cvtpk(p1[2 * i], p1[2 * i + 1]);
        }
        bf16x8 pf[4];
        pf[0] = mkfrag(wa[0], wa[1], wa[2], wa[3], hi);   // keys  0..15
        pf[1] = mkfrag(wa[4], wa[5], wa[6], wa[7], hi);   // keys 16..31
        pf[2] = mkfrag(wb[0], wb[1], wb[2], wb[3], hi);   // keys 32..47
        pf[3] = mkfrag(wb[4], wb[5], wb[6], wb[7], hi);   // keys 48..63

        // ---- O^T += V^T P^T
        __builtin_amdgcn_s_setprio(1);
        #pragma unroll
        for (int ks = 0; ks < 4; ++ks) {
            s16x8 vf0 = *(const s16x8*)&Vl[cur][((ks * 2 + 0) * 64 + ln) * 8];
            s16x8 vf1 = *(const s16x8*)&Vl[cur][((ks * 2 + 1) * 64 + ln) * 8];
            oacc0 = __builtin_amdgcn_mfma_f32_32x32x16_bf16(
                    __builtin_bit_cast(bf16x8, vf0), pf[ks], oacc0, 0, 0, 0);
            oacc1 = __builtin_amdgcn_mfma_f32_32x32x16_bf16(
                    __builtin_bit_cast(bf16x8, vf1), pf[ks], oacc1, 0, 0, 0);
        }
        __builtin_amdgcn_s_setprio(0);

        __syncthreads();   // drains prefetch vmcnt; all waves done with cur
    };

    for (int it = 0; it < NTILE; it += 2) {
        body(it, 0);       // compile-time cur -> immediate LDS offsets
        body(it + 1, 1);
    }

    // ---- epilogue
    const float lt  = l + __shfl_xor(l, 32);
    const float inv = 1.0f / lt;
    float* Orow = Oh + (size_t)(q0 + r31) * DH;
    #pragma unroll
    for (int g = 0; g < 4; ++g) {
        float4 o0 = { oacc0[4*g] * inv, oacc0[4*g+1] * inv,
                      oacc0[4*g+2] * inv, oacc0[4*g+3] * inv };
        *(float4*)&Orow[g * 8 + hi * 4] = o0;
        float4 o1 = { oacc1[4*g] * inv, oacc1[4*g+1] * inv,
                      oacc1[4*g+2] * inv, oacc1[4*g+3] * inv };
        *(float4*)&Orow[32 + g * 8 + hi * 4] = o1;
    }
}

// ---------------- fallback (fp32 in, self-staging, round-1 proven) ------
static __device__ __forceinline__ int swz_fb(int row, int col) {
    return row * 64 + (col ^ ((row & 7) << 3));
}

__global__ __launch_bounds__(256) void sdpa_fwd_fb(
        const float* __restrict__ Q, const float* __restrict__ K,
        const float* __restrict__ V, float* __restrict__ O)
{
    __shared__ __attribute__((aligned(16))) unsigned short Klf[BK * DH];
    __shared__ __attribute__((aligned(16))) unsigned short Vtf[DH * BK];
    __shared__ __attribute__((aligned(16))) unsigned short Plf[4][16 * BK];

    const int tid = threadIdx.x;
    const int w = tid >> 6, ln = tid & 63, lg = ln >> 4, lr = ln & 15;
    const int n = blockIdx.x >> 5, qt = blockIdx.x & 31;
    const int q0 = qt * 64 + w * 16;
    const size_t hoff = (size_t)n * S_LEN * DH;
    const float *Qh = Q + hoff, *Kh = K + hoff, *Vh = V + hoff;
    float* Oh = O + hoff;

    s16x8 qf[2];
    #pragma unroll
    for (int t = 0; t < 2; ++t) {
        const float* src = Qh + (size_t)(q0 + lr) * DH + t * 32 + lg * 8;
        float4 a = *(const float4*)(src);
        float4 b = *(const float4*)(src + 4);
        s16x8 v;
        v[0] = (short)f2bf(a.x * 0.125f); v[1] = (short)f2bf(a.y * 0.125f);
        v[2] = (short)f2bf(a.z * 0.125f); v[3] = (short)f2bf(a.w * 0.125f);
        v[4] = (short)f2bf(b.x * 0.125f); v[5] = (short)f2bf(b.y * 0.125f);
        v[6] = (short)f2bf(b.z * 0.125f); v[7] = (short)f2bf(b.w * 0.125f);
        qf[t] = v;
    }
    float mrow[4] = {-INFINITY, -INFINITY, -INFINITY, -INFINITY};
    float lrow[4] = {0.f, 0.f, 0.f, 0.f};
    f32x4 oacc[4];
    #pragma unroll
    for (int nn = 0; nn < 4; ++nn) oacc[nn] = (f32x4){0.f, 0.f, 0.f, 0.f};

    for (int it = 0; it < NTILE; ++it) {
        const int k0 = it * BK;
        __syncthreads();
        #pragma unroll
        for (int r4 = 0; r4 < 4; ++r4) {
            const int lin = tid + 256 * r4;
            const int row = lin >> 4, c4 = lin & 15;
            float4 kv = *(const float4*)(Kh + (size_t)(k0 + row) * DH + c4 * 4);
            u16x4 kb;
            kb[0] = f2bf(kv.x); kb[1] = f2bf(kv.y); kb[2] = f2bf(kv.z); kb[3] = f2bf(kv.w);
            *(u16x4*)&Klf[swz_fb(row, c4 * 4)] = kb;
            float4 vv = *(const float4*)(Vh + (size_t)(k0 + row) * DH + c4 * 4);
            const float vals[4] = {vv.x, vv.y, vv.z, vv.w};
            #pragma unroll
            for (int ii = 0; ii < 4; ++ii) Vtf[swz_fb(c4 * 4 + ii, row)] = f2bf(vals[ii]);
        }
        __syncthreads();
        f32x4 sacc[4];
        #pragma unroll
        for (int kt = 0; kt < 4; ++kt) {
            f32x4 acc = (f32x4){0.f, 0.f, 0.f, 0.f};
            #pragma unroll
            for (int t = 0; t < 2; ++t) {
                s16x8 kf = *(const s16x8*)&Klf[swz_fb(kt * 16 + lr, t * 32 + lg * 8)];
                acc = __builtin_amdgcn_mfma_f32_16x16x32_bf16(
                        __builtin_bit_cast(bf16x8, qf[t]),
                        __builtin_bit_cast(bf16x8, kf), acc, 0, 0, 0);
            }
            sacc[kt] = acc;
        }
        float alpha[4];
        #pragma unroll
        for (int j = 0; j < 4; ++j) {
            float v = fmaxf(fmaxf(sacc[0][j], sacc[1][j]), fmaxf(sacc[2][j], sacc[3][j]));
            #pragma unroll
            for (int off = 1; off < 16; off <<= 1) v = fmaxf(v, __shfl_xor(v, off));
            const float mn = fmaxf(mrow[j], v);
            alpha[j] = __expf(mrow[j] - mn);
            mrow[j] = mn;
        }
        float psum[4] = {0.f, 0.f, 0.f, 0.f};
        #pragma unroll
        for (int kt = 0; kt < 4; ++kt) {
            #pragma unroll
            for (int j = 0; j < 4; ++j) {
                const float p = __expf(sacc[kt][j] - mrow[j]);
                const unsigned short pb = f2bf(p);
                unsigned int pu = ((unsigned int)pb) << 16;
                psum[j] += __builtin_bit_cast(float, pu);
                Plf[w][swz_fb(lg * 4 + j, kt * 16 + lr)] = pb;
            }
        }
        #pragma unroll
        for (int j = 0; j < 4; ++j) {
            float s = psum[j];
            #pragma unroll
            for (int off = 1; off < 16; off <<= 1) s += __shfl_xor(s, off);
            lrow[j] = lrow[j] * alpha[j] + s;
        }
        #pragma unroll
        for (int nn = 0; nn < 4; ++nn) {
            #pragma unroll
            for (int j = 0; j < 4; ++j) oacc[nn][j] *= alpha[j];
        }
        #pragma unroll
        for (int t = 0; t < 2; ++t) {
            s16x8 pf = *(const s16x8*)&Plf[w][swz_fb(lr, t * 32 + lg * 8)];
            #pragma unroll
            for (int nn = 0; nn < 4; ++nn) {
                s16x8 vf = *(const s16x8*)&Vtf[swz_fb(nn * 16 + lr, t * 32 + lg * 8)];
                oacc[nn] = __builtin_amdgcn_mfma_f32_16x16x32_bf16(
                        __builtin_bit_cast(bf16x8, pf),
                        __builtin_bit_cast(bf16x8, vf), oacc[nn], 0, 0, 0);
            }
        }
    }
    #pragma unroll
    for (int j = 0; j < 4; ++j) {
        const float inv = 1.0f / lrow[j];
        #pragma unroll
        for (int nn = 0; nn < 4; ++nn)
            Oh[(size_t)(q0 + lg * 4 + j) * DH + nn * 16 + lr] = oacc[nn][j] * inv;
    }
}

extern "C" void kernel_launch(void* const* d_in, const int* in_sizes, int n_in,
                              void* d_out, int out_size, void* d_ws, size_t ws_size,
                              hipStream_t stream) {
    const float* Q = (const float*)d_in[0];
    const float* K = (const float*)d_in[1];
    const float* V = (const float*)d_in[2];
    float* O = (float*)d_out;

    const size_t elems = (size_t)NH * S_LEN * DH;
    const size_t bf_bytes = elems * 2;
    if (ws_size >= 3 * bf_bytes) {
        unsigned short* Qf = (unsigned short*)d_ws;
        unsigned short* Kf = Qf + elems;
        unsigned short* Vf = Kf + elems;
        prepass<<<NH * 32, 256, 0, stream>>>(Q, K, V, Qf, Kf, Vf);
        sdpa32<<<NH * (S_LEN / QBLK), 256, 0, stream>>>(Qf, Kf, Vf, O);
    } else {
        sdpa_fwd_fb<<<NH * (S_LEN / 64), 256, 0, stream>>>(Q, K, V, O);
    }
}